// Round 10
// baseline (926.134 us; speedup 1.0000x reference)
//
#include <hip/hip_runtime.h>
#include <math.h>

#define BSZ 4
#define NXN 4096
#define NPARP 5
#define HD 128
#define NLAY 6
#define KNN 16
#define DTC 0.1f
#define EPSC 1e-5f
#define NN (BSZ * NXN)
#define NPB 8          // nodes per block in kmsg8

typedef __attribute__((ext_vector_type(8))) short short8;
typedef __attribute__((ext_vector_type(4))) float f32x4;

#define XR(r) (((r) & 7) << 4)

// LDS byte offsets for kmsg8 (halved E, no fi/AU staging)
#define OFF_E   0        // 64 x 256B  (fj bf16 -> h bf16, per half)
#define OFF_AG  16384    // 16 x 256B  (agg bf16; rows 8-15 garbage)
#define OFF_HU  20480    // 16 x 256B  (update hidden bf16; rows 8-15 garbage)
#define OFF_DU  24576    // 128 f32
#define OFF_DPX 25088
#define OFF_DPY 25600
#define OFF_VAR 26112    // [8][8] f32
#define SMEMB   26368

__device__ __forceinline__ float swishf(float x) {
    return x * __builtin_amdgcn_rcpf(1.0f + __expf(-x));
}

// round-to-nearest bf16 (weights only)
__device__ __forceinline__ unsigned short f2bf(float x) {
    union { float f; unsigned u; } v; v.f = x;
    unsigned r = v.u + 0x7fffu + ((v.u >> 16) & 1u);
    return (unsigned short)(r >> 16);
}
// truncation bf16 (activations)
__device__ __forceinline__ unsigned short trh(float x) {
    union { float f; unsigned u; } v; v.f = x;
    return (unsigned short)(v.u >> 16);
}
__device__ __forceinline__ unsigned trpk(float lo, float hi) {
    union { float f; unsigned u; } a, b; a.f = lo; b.f = hi;
    return (b.u & 0xFFFF0000u) | (a.u >> 16);
}

// ---------------- grid min/max per batch ----------------
__global__ void kminmax(const float* __restrict__ grid, float* __restrict__ gmm) {
    int b = blockIdx.x;
    int t = threadIdx.x;
    float mnx = 1e30f, mxx = -1e30f, mny = 1e30f, mxy = -1e30f;
    for (int n = t; n < NXN; n += 256) {
        float x = grid[(b * NXN + n) * 2 + 0];
        float y = grid[(b * NXN + n) * 2 + 1];
        mnx = fminf(mnx, x); mxx = fmaxf(mxx, x);
        mny = fminf(mny, y); mxy = fmaxf(mxy, y);
    }
    __shared__ float s[4][256];
    s[0][t] = mnx; s[1][t] = mxx; s[2][t] = mny; s[3][t] = mxy;
    __syncthreads();
    for (int off = 128; off > 0; off >>= 1) {
        if (t < off) {
            s[0][t] = fminf(s[0][t], s[0][t + off]);
            s[1][t] = fmaxf(s[1][t], s[1][t + off]);
            s[2][t] = fminf(s[2][t], s[2][t + off]);
            s[3][t] = fmaxf(s[3][t], s[3][t + off]);
        }
        __syncthreads();
    }
    if (t == 0) {
        gmm[b * 4 + 0] = s[0][0];
        gmm[b * 4 + 1] = s[1][0];
        gmm[b * 4 + 2] = s[2][0];
        gmm[b * 4 + 3] = s[3][0];
    }
}

// ---------------- pos + sq ----------------
__global__ void kpos(const float* __restrict__ grid, const float* __restrict__ gmm,
                     float* __restrict__ pos, float* __restrict__ sq) {
    int g = blockIdx.x * 256 + threadIdx.x;
    if (g >= NN) return;
    int b = g >> 12;
    float gx = grid[g * 2], gy = grid[g * 2 + 1];
    float px = (gx - gmm[b * 4 + 0]) / (gmm[b * 4 + 1] - gmm[b * 4 + 0]);
    float py = (gy - gmm[b * 4 + 2]) / (gmm[b * 4 + 3] - gmm[b * 4 + 2]);
    pos[g * 2] = px; pos[g * 2 + 1] = py;
    sq[g] = __fadd_rn(__fmul_rn(px, px), __fmul_rn(py, py));
}

// ---------------- KNN: one wave per node, chunked LDS, 16 extraction rounds ----
__global__ __launch_bounds__(256) void kknnC(const float* __restrict__ pos,
                                             const float* __restrict__ sq,
                                             int* __restrict__ idxw) {
    __shared__ float2 sxy[1024];
    __shared__ float ssq[1024];
    int blk = blockIdx.x;
    int b = blk >> 10;
    int t = threadIdx.x;
    int lane = t & 63, w = t >> 6;
    int i = (blk & 1023) * 4 + w;
    float2 pi = *(const float2*)&pos[(b * NXN + i) * 2];
    float sqi = sq[b * NXN + i];
    float pk[64];
    float g[4];
#pragma unroll
    for (int c = 0; c < 4; ++c) {
        __syncthreads();
        for (int n = t; n < 1024; n += 256) {
            int j = b * NXN + c * 1024 + n;
            sxy[n] = *(const float2*)&pos[j * 2];
            ssq[n] = sq[j];
        }
        __syncthreads();
        float gc = 1e38f;
#pragma unroll
        for (int tt = 0; tt < 16; ++tt) {
            int n = tt * 64 + lane;
            float2 pj = sxy[n];
            float dot = fmaf(pi.x, pj.x, pi.y * pj.y);
            float d2 = (sqi + ssq[n]) - 2.0f * dot;
            d2 = (c * 1024 + n == i) ? 1e38f : d2;
            pk[c * 16 + tt] = d2;
            gc = fminf(gc, d2);
        }
        g[c] = gc;
    }
    int obase = (b * NXN + i) * KNN;
#pragma unroll 1
    for (int r = 0; r < KNN; ++r) {
        float m = fminf(fminf(g[0], g[1]), fminf(g[2], g[3]));
        float gm = m;
#pragma unroll
        for (int off = 1; off < 64; off <<= 1)
            gm = fminf(gm, __shfl_xor(gm, off));
        if (m == gm) {
            int jt = 0;
            if (g[0] == gm) {
                float ng = 1e38f;
#pragma unroll
                for (int tt = 0; tt < 16; ++tt) {
                    bool hit = (pk[tt] == gm);
                    jt = hit ? tt : jt;
                    pk[tt] = hit ? 1e38f : pk[tt];
                    ng = fminf(ng, pk[tt]);
                }
                g[0] = ng;
            }
            if (g[1] == gm) {
                float ng = 1e38f;
#pragma unroll
                for (int tt = 16; tt < 32; ++tt) {
                    bool hit = (pk[tt] == gm);
                    jt = hit ? tt : jt;
                    pk[tt] = hit ? 1e38f : pk[tt];
                    ng = fminf(ng, pk[tt]);
                }
                g[1] = ng;
            }
            if (g[2] == gm) {
                float ng = 1e38f;
#pragma unroll
                for (int tt = 32; tt < 48; ++tt) {
                    bool hit = (pk[tt] == gm);
                    jt = hit ? tt : jt;
                    pk[tt] = hit ? 1e38f : pk[tt];
                    ng = fminf(ng, pk[tt]);
                }
                g[2] = ng;
            }
            if (g[3] == gm) {
                float ng = 1e38f;
#pragma unroll
                for (int tt = 48; tt < 64; ++tt) {
                    bool hit = (pk[tt] == gm);
                    jt = hit ? tt : jt;
                    pk[tt] = hit ? 1e38f : pk[tt];
                    ng = fminf(ng, pk[tt]);
                }
                g[3] = ng;
            }
            idxw[obase + r] = ((jt >> 4) << 10) + ((jt & 15) << 6) + lane;
        }
    }
}

// ---- weight pack: W[K x 128] f32 -> bf16 [ceil8(K)][128][8], col-pair permuted ----
__global__ void kpack(const float* __restrict__ src, unsigned short* __restrict__ dst,
                      int K, int KB, int nmat) {
    int g = blockIdx.x * 256 + threadIdx.x;
    int per = KB * 1024;
    if (g >= nmat * per) return;
    int mat = g / per, rem = g % per;
    int kb = rem >> 10, r2 = rem & 1023;
    int n = r2 >> 3, j = r2 & 7;
    int phys = (n & 96) | ((n & 15) << 1) | ((n >> 4) & 1);
    int k = kb * 8 + j;
    float v = (k < K) ? src[(mat * K + k) * HD + phys] : 0.0f;
    dst[g] = f2bf(v);
}

// ---------------- embedding MLP ----------------
__global__ __launch_bounds__(128) void kembed(const float* __restrict__ inputs,
                                              const float* __restrict__ pos,
                                              const float* __restrict__ params,
                                              const float* __restrict__ w1,
                                              const float* __restrict__ b1,
                                              const float* __restrict__ w2,
                                              const float* __restrict__ b2,
                                              float* __restrict__ f,
                                              unsigned short* __restrict__ fh) {
    __shared__ __align__(16) float sh[HD];
    int t = threadIdx.x;
    int g = blockIdx.x;
    float rw1[8];
#pragma unroll
    for (int k = 0; k < 8; k++) rw1[k] = w1[k * HD + t];
    float u = inputs[g];
    float px = pos[g * 2], py = pos[g * 2 + 1];
    float a = b1[t] + u * rw1[0] + px * rw1[1] + py * rw1[2];
#pragma unroll
    for (int j = 0; j < NPARP; j++) a += params[g * NPARP + j] * rw1[3 + j];
    sh[t] = swishf(a);
    __syncthreads();
    float a2 = b2[t];
    for (int k = 0; k < HD; k += 4) {
        float4 s4 = *(const float4*)&sh[k];
        a2 = fmaf(s4.x, w2[(k + 0) * HD + t], a2);
        a2 = fmaf(s4.y, w2[(k + 1) * HD + t], a2);
        a2 = fmaf(s4.z, w2[(k + 2) * HD + t], a2);
        a2 = fmaf(s4.w, w2[(k + 3) * HD + t], a2);
    }
    float fv = swishf(a2);
    f[g * HD + t] = fv;
    fh[g * HD + t] = trh(fv);
}

// -------- fused MFMA layer: phase-local weights, no cross-phase register state --------
__global__ __launch_bounds__(256, 4) void kmsg8(
    const float* __restrict__ f, const unsigned short* __restrict__ fh,
    float* __restrict__ fnew,
    const float* __restrict__ inputs, const float* __restrict__ pos,
    const float* __restrict__ params, const int* __restrict__ idxw,
    const unsigned short* __restrict__ W1p, const float* __restrict__ W1r,
    const float* __restrict__ B1,
    const unsigned short* __restrict__ W2p, const float* __restrict__ B2,
    const unsigned short* __restrict__ U1p, const float* __restrict__ U1r,
    const float* __restrict__ UB1,
    const unsigned short* __restrict__ U2p, const float* __restrict__ UB2,
    float* __restrict__ p1, float* __restrict__ p2) {
    __shared__ __align__(16) char sm[SMEMB];
    int tid = threadIdx.x;
    int lane = tid & 63, w = tid >> 6;
    int l15 = lane & 15, l4 = lane >> 4;
    int bn0 = blockIdx.x * NPB;
    int base = bn0 & ~(NXN - 1);
    int bb = bn0 >> 12;
    int c0 = w * 32 + l15, c1 = c0 + 16;          // logical tile cols (packed arrays)
    int pc0 = w * 32 + 2 * l15, pc1 = pc0 + 1;    // physical cols
    float* sVAR = (float*)(sm + OFF_VAR);

    // ---- staging: du/dpx/dpy + var
    if (lane < 32) {
        int e = w * 32 + lane;
        int nd = e >> 4;
        int gj = idxw[(bn0 + nd) * KNN + (e & 15)];
        int gn = base + gj;
        ((float*)(sm + OFF_DU))[e]  = inputs[bn0 + nd] - inputs[gn];
        ((float*)(sm + OFF_DPX))[e] = pos[(bn0 + nd) * 2]     - pos[gn * 2];
        ((float*)(sm + OFF_DPY))[e] = pos[(bn0 + nd) * 2 + 1] - pos[gn * 2 + 1];
    } else if (lane < 42) {
        int q = lane - 32;
        int nd = 2 * w + q / 5, j = q % 5;
        sVAR[nd * 8 + j] = params[(bn0 + nd) * NPARP + j];
    }

#define GATHER(H) {                                                         \
        int r = tid >> 2, q = tid & 3;                                      \
        int e = (H) * 64 + r;                                               \
        int gj = idxw[(bn0 + (e >> 4)) * KNN + (e & 15)];                   \
        const uint4* srcp = (const uint4*)(fh + (base + gj) * HD);          \
        char* drow = sm + OFF_E + r * 256;                                  \
        _Pragma("unroll")                                                   \
        for (int jj = 0; jj < 4; ++jj) {                                    \
            uint4 pv = srcp[q * 4 + jj];                                    \
            *(uint4*)(drow + ((q * 64 + jj * 16) ^ XR(r))) = pv;            \
        } }

    GATHER(0)
    __syncthreads();               // staging + half0 gather complete

    // ---- com GEMM (phase-local: afi + bC die at end of this block)
    f32x4 cm0 = {0.f, 0.f, 0.f, 0.f}, cm1 = {0.f, 0.f, 0.f, 0.f};
    {
        int fiRow = bn0 + l15;
        const char* fiP = (const char*)(fh + fiRow * HD);
#pragma unroll
        for (int k = 0; k < 4; ++k) {
            short8 afi = *(const short8*)(fiP + k * 64 + l4 * 16);
            short8 bC0 = *(const short8*)&W1p[((k * 4 + l4) * HD + c0) * 8];
            short8 bC1 = *(const short8*)&W1p[((k * 4 + l4) * HD + c1) * 8];
            cm0 = __builtin_amdgcn_mfma_f32_16x16x32_bf16(afi, bC0, cm0, 0, 0, 0);
            cm1 = __builtin_amdgcn_mfma_f32_16x16x32_bf16(afi, bC1, cm1, 0, 0, 0);
        }
        if (l4 < 2) {              // fold bias + var (valid node rows only)
            float vB1_0 = B1[pc0], vB1_1 = B1[pc1];
            float wv0[5], wv1[5];
#pragma unroll
            for (int j = 0; j < 5; ++j) {
                wv0[j] = W1r[(259 + j) * HD + pc0];
                wv1[j] = W1r[(259 + j) * HD + pc1];
            }
#pragma unroll
            for (int reg = 0; reg < 4; ++reg) {
                int nd = l4 * 4 + reg;
                float s0 = vB1_0, s1 = vB1_1;
#pragma unroll
                for (int j = 0; j < 5; ++j) {
                    float vv = sVAR[nd * 8 + j];
                    s0 = fmaf(vv, wv0[j], s0);
                    s1 = fmaf(vv, wv1[j], s1);
                }
                cm0[reg] += s0; cm1[reg] += s1;
            }
        }
    }
    float wdu0 = W1r[256 * HD + pc0], wdx0 = W1r[257 * HD + pc0], wdy0 = W1r[258 * HD + pc0];
    float wdu1 = W1r[256 * HD + pc1], wdx1 = W1r[257 * HD + pc1], wdy1 = W1r[258 * HD + pc1];

#define MM1_HALF(H) {                                                       \
        short8 bM10[4], bM11[4];                                            \
        _Pragma("unroll")                                                   \
        for (int k = 0; k < 4; ++k) {                                       \
            bM10[k] = *(const short8*)&W1p[((16 + k * 4 + l4) * HD + c0) * 8]; \
            bM11[k] = *(const short8*)&W1p[((16 + k * 4 + l4) * HD + c1) * 8]; \
        }                                                                   \
        _Pragma("unroll")                                                   \
        for (int m = 0; m < 4; ++m) {                                       \
            short8 aC[4];                                                   \
            _Pragma("unroll")                                               \
            for (int k = 0; k < 4; ++k)                                     \
                aC[k] = *(short8*)(sm + OFF_E + (m * 16 + l15) * 256 +      \
                                   ((k * 64 + l4 * 16) ^ XR(m * 16 + l15))); \
            f32x4 h0 = {0.f, 0.f, 0.f, 0.f}, h1 = {0.f, 0.f, 0.f, 0.f};     \
            _Pragma("unroll")                                               \
            for (int k = 0; k < 4; ++k) {                                   \
                h0 = __builtin_amdgcn_mfma_f32_16x16x32_bf16(aC[k], bM10[k], h0, 0, 0, 0); \
                h1 = __builtin_amdgcn_mfma_f32_16x16x32_bf16(aC[k], bM11[k], h1, 0, 0, 0); \
            }                                                               \
            int M = (H) * 4 + m;                                            \
            float com0 = __shfl(cm0[M & 3], ((M >> 2) << 4) | l15);         \
            float com1 = __shfl(cm1[M & 3], ((M >> 2) << 4) | l15);         \
            float4 duv = *(const float4*)(sm + OFF_DU  + ((H) * 64 + m * 16 + l4 * 4) * 4); \
            float4 dxv = *(const float4*)(sm + OFF_DPX + ((H) * 64 + m * 16 + l4 * 4) * 4); \
            float4 dyv = *(const float4*)(sm + OFF_DPY + ((H) * 64 + m * 16 + l4 * 4) * 4); \
            __syncthreads();                                                \
            _Pragma("unroll")                                               \
            for (int reg = 0; reg < 4; ++reg) {                             \
                int rr = m * 16 + l4 * 4 + reg;                             \
                float d_u = ((const float*)&duv)[reg];                      \
                float d_x = ((const float*)&dxv)[reg];                      \
                float d_y = ((const float*)&dyv)[reg];                      \
                float hv0 = h0[reg] + com0 + d_u * wdu0 + d_x * wdx0 + d_y * wdy0; \
                float hv1 = h1[reg] + com1 + d_u * wdu1 + d_x * wdx1 + d_y * wdy1; \
                *(unsigned*)(sm + OFF_E + rr * 256 + ((w * 64 + l15 * 4) ^ XR(rr))) = \
                    trpk(swishf(hv0), swishf(hv1));                         \
            }                                                               \
        } }

#define MM2_HALF(H) {                                                       \
        short8 bM20[4], bM21[4];                                            \
        _Pragma("unroll")                                                   \
        for (int k = 0; k < 4; ++k) {                                       \
            bM20[k] = *(const short8*)&W2p[((k * 4 + l4) * HD + c0) * 8];   \
            bM21[k] = *(const short8*)&W2p[((k * 4 + l4) * HD + c1) * 8];   \
        }                                                                   \
        float vB2_0 = B2[pc0], vB2_1 = B2[pc1];                             \
        _Pragma("unroll")                                                   \
        for (int m = 0; m < 4; ++m) {                                       \
            short8 hf4[4];                                                  \
            _Pragma("unroll")                                               \
            for (int k = 0; k < 4; ++k)                                     \
                hf4[k] = *(short8*)(sm + OFF_E + (m * 16 + l15) * 256 +     \
                                    ((k * 64 + l4 * 16) ^ XR(m * 16 + l15))); \
            f32x4 s0 = {0.f, 0.f, 0.f, 0.f}, s1 = {0.f, 0.f, 0.f, 0.f};     \
            _Pragma("unroll")                                               \
            for (int k = 0; k < 4; ++k) {                                   \
                s0 = __builtin_amdgcn_mfma_f32_16x16x32_bf16(hf4[k], bM20[k], s0, 0, 0, 0); \
                s1 = __builtin_amdgcn_mfma_f32_16x16x32_bf16(hf4[k], bM21[k], s1, 0, 0, 0); \
            }                                                               \
            float sum0 = swishf(s0[0] + vB2_0) + swishf(s0[1] + vB2_0)      \
                       + swishf(s0[2] + vB2_0) + swishf(s0[3] + vB2_0);     \
            float sum1 = swishf(s1[0] + vB2_1) + swishf(s1[1] + vB2_1)      \
                       + swishf(s1[2] + vB2_1) + swishf(s1[3] + vB2_1);     \
            sum0 += __shfl_xor(sum0, 16); sum0 += __shfl_xor(sum0, 32);     \
            sum1 += __shfl_xor(sum1, 16); sum1 += __shfl_xor(sum1, 32);     \
            int M = (H) * 4 + m;                                            \
            if (lane < 16) {                                                \
                *(unsigned*)(sm + OFF_AG + M * 256 + ((w * 64 + lane * 4) ^ XR(M))) = \
                    trpk(sum0 * 0.0625f, sum1 * 0.0625f);                   \
            }                                                               \
        } }

    // ---- half 0
    MM1_HALF(0)
    __syncthreads();               // h half0 complete
    MM2_HALF(0)
    __syncthreads();               // E free
    // ---- half 1
    GATHER(1)
    __syncthreads();               // half1 gather complete
    MM1_HALF(1)
    __syncthreads();               // h half1 complete
    MM2_HALF(1)
    __syncthreads();               // agg complete

    // ---- upd1: K=256 ([fi(global frags) | agg(LDS)]) -> swish -> sHU
    {
        int fiRow = bn0 + l15;
        const char* fiP = (const char*)(fh + fiRow * HD);
        f32x4 u0 = {0.f, 0.f, 0.f, 0.f}, u1 = {0.f, 0.f, 0.f, 0.f};
#pragma unroll
        for (int k = 0; k < 4; ++k) {
            short8 afi = *(const short8*)(fiP + k * 64 + l4 * 16);
            short8 b0 = *(const short8*)&U1p[((k * 4 + l4) * HD + c0) * 8];
            short8 b1 = *(const short8*)&U1p[((k * 4 + l4) * HD + c1) * 8];
            u0 = __builtin_amdgcn_mfma_f32_16x16x32_bf16(afi, b0, u0, 0, 0, 0);
            u1 = __builtin_amdgcn_mfma_f32_16x16x32_bf16(afi, b1, u1, 0, 0, 0);
        }
#pragma unroll
        for (int k = 0; k < 4; ++k) {
            short8 ag = *(short8*)(sm + OFF_AG + l15 * 256 +
                                   ((k * 64 + l4 * 16) ^ XR(l15)));
            short8 b0 = *(const short8*)&U1p[(((4 + k) * 4 + l4) * HD + c0) * 8];
            short8 b1 = *(const short8*)&U1p[(((4 + k) * 4 + l4) * HD + c1) * 8];
            u0 = __builtin_amdgcn_mfma_f32_16x16x32_bf16(ag, b0, u0, 0, 0, 0);
            u1 = __builtin_amdgcn_mfma_f32_16x16x32_bf16(ag, b1, u1, 0, 0, 0);
        }
        if (l4 < 2) {
            float vUB1_0 = UB1[pc0], vUB1_1 = UB1[pc1];
            float uv0[5], uv1[5];
#pragma unroll
            for (int j = 0; j < 5; ++j) {
                uv0[j] = U1r[(256 + j) * HD + pc0];
                uv1[j] = U1r[(256 + j) * HD + pc1];
            }
#pragma unroll
            for (int reg = 0; reg < 4; ++reg) {
                int nd = l4 * 4 + reg;
                float s0 = vUB1_0, s1 = vUB1_1;
#pragma unroll
                for (int j = 0; j < 5; ++j) {
                    float vv = sVAR[nd * 8 + j];
                    s0 = fmaf(vv, uv0[j], s0);
                    s1 = fmaf(vv, uv1[j], s1);
                }
                *(unsigned*)(sm + OFF_HU + nd * 256 + ((w * 64 + l15 * 4) ^ XR(nd))) =
                    trpk(swishf(u0[reg] + s0), swishf(u1[reg] + s1));
            }
        }
    }
    __syncthreads();               // hu complete

    // ---- upd2: K=128 -> residual -> fnew + fused stats
    {
        f32x4 o0 = {0.f, 0.f, 0.f, 0.f}, o1 = {0.f, 0.f, 0.f, 0.f};
#pragma unroll
        for (int k = 0; k < 4; ++k) {
            short8 ah = *(short8*)(sm + OFF_HU + l15 * 256 +
                                   ((k * 64 + l4 * 16) ^ XR(l15)));
            short8 b0 = *(const short8*)&U2p[((k * 4 + l4) * HD + c0) * 8];
            short8 b1 = *(const short8*)&U2p[((k * 4 + l4) * HD + c1) * 8];
            o0 = __builtin_amdgcn_mfma_f32_16x16x32_bf16(ah, b0, o0, 0, 0, 0);
            o1 = __builtin_amdgcn_mfma_f32_16x16x32_bf16(ah, b1, o1, 0, 0, 0);
        }
        float vUB2_0 = UB2[pc0], vUB2_1 = UB2[pc1];
        float a1_0 = 0.f, a2_0 = 0.f, a1_1 = 0.f, a2_1 = 0.f;
        if (l4 < 2) {
#pragma unroll
            for (int reg = 0; reg < 4; ++reg) {
                int nd = l4 * 4 + reg;
                int gi = (bn0 + nd) * HD + pc0;
                float2 fv = *(const float2*)&f[gi];
                float v0 = fv.x + swishf(o0[reg] + vUB2_0);
                float v1 = fv.y + swishf(o1[reg] + vUB2_1);
                float2 st = {v0, v1};
                *(float2*)&fnew[gi] = st;
                a1_0 += v0; a2_0 += v0 * v0;
                a1_1 += v1; a2_1 += v1 * v1;
            }
        }
        a1_0 += __shfl_xor(a1_0, 16); a2_0 += __shfl_xor(a2_0, 16);
        a1_1 += __shfl_xor(a1_1, 16); a2_1 += __shfl_xor(a2_1, 16);
        if (l4 == 0) {
            atomicAdd(&p1[bb * HD + pc0], a1_0);
            atomicAdd(&p2[bb * HD + pc0], a2_0);
            atomicAdd(&p1[bb * HD + pc1], a1_1);
            atomicAdd(&p2[bb * HD + pc1], a2_1);
        }
    }
#undef GATHER
#undef MM1_HALF
#undef MM2_HALF
}

// ---------------- fused finalize + apply ----------------
__global__ void kapply(const float* __restrict__ fnew,
                       const float* __restrict__ p1, const float* __restrict__ p2,
                       float* __restrict__ f, unsigned short* __restrict__ fh) {
    int g = blockIdx.x * 256 + threadIdx.x;
    int b = g >> 19;
    int c = g & 127;
    float m = p1[b * HD + c] * (1.0f / NXN);
    float v = p2[b * HD + c] * (1.0f / NXN) - m * m;
    float fv = (fnew[g] - m) * rsqrtf(v + EPSC);
    f[g] = fv;
    fh[g] = trh(fv);
}

// ---------------- output head ----------------
__global__ __launch_bounds__(64) void khead(const float* __restrict__ f,
                                            const float* __restrict__ inputs,
                                            const float* __restrict__ ow1,
                                            const float* __restrict__ ob1,
                                            const float* __restrict__ ow2,
                                            const float* __restrict__ ob2,
                                            float* __restrict__ out) {
    int bn = blockIdx.x;
    int c = threadIdx.x;
    float a = ob1[c];
    for (int k = 0; k < HD; k++) a += f[bn * HD + k] * ow1[k * 64 + c];
    float v = swishf(a) * ow2[c];
#pragma unroll
    for (int off = 32; off > 0; off >>= 1) v += __shfl_down(v, off);
    if (c == 0) out[bn] = inputs[bn] + DTC * (v + ob2[0]);
}

extern "C" void kernel_launch(void* const* d_in, const int* in_sizes, int n_in,
                              void* d_out, int out_size, void* d_ws, size_t ws_size,
                              hipStream_t stream) {
    const float* inputs = (const float*)d_in[0];
    const float* params = (const float*)d_in[1];
    const float* grid   = (const float*)d_in[3];
    const float* emb_w1 = (const float*)d_in[4];
    const float* emb_b1 = (const float*)d_in[5];
    const float* emb_w2 = (const float*)d_in[6];
    const float* emb_b2 = (const float*)d_in[7];
    const float* mw1 = (const float*)d_in[8];
    const float* mb1 = (const float*)d_in[9];
    const float* mw2 = (const float*)d_in[10];
    const float* mb2 = (const float*)d_in[11];
    const float* uw1 = (const float*)d_in[12];
    const float* ub1 = (const float*)d_in[13];
    const float* uw2 = (const float*)d_in[14];
    const float* ub2 = (const float*)d_in[15];
    const float* ow1 = (const float*)d_in[16];
    const float* ob1 = (const float*)d_in[17];
    const float* ow2 = (const float*)d_in[18];
    const float* ob2 = (const float*)d_in[19];
    float* out = (float*)d_out;

    float* ws  = (float*)d_ws;
    float* pos = ws;                      // BS*NX*2
    float* sq  = pos + BSZ * NXN * 2;     // BS*NX
    float* f   = sq + BSZ * NXN;          // BS*NX*H
    float* fnew = f + BSZ * NXN * HD;     // BS*NX*H
    float* p1   = fnew + BSZ * NXN * HD;  // BS*H
    float* p2   = p1 + BSZ * HD;          // BS*H  (contiguous with p1)
    float* gmm  = p2 + BSZ * HD;          // 16
    int* idxw   = (int*)(gmm + 16);       // BS*NX*K ints
    unsigned short* mw1p = (unsigned short*)(idxw + NN * KNN);  // 6*33*1024
    unsigned short* mw2p = mw1p + 6 * 33 * 1024;                // 6*16*1024
    unsigned short* uw1p = mw2p + 6 * 16 * 1024;                // 6*33*1024
    unsigned short* uw2p = uw1p + 6 * 33 * 1024;                // 6*16*1024
    unsigned short* fh   = uw2p + 6 * 16 * 1024;                // BS*NX*H bf16

    kminmax<<<BSZ, 256, 0, stream>>>(grid, gmm);
    kpos<<<NN / 256, 256, 0, stream>>>(grid, gmm, pos, sq);
    kknnC<<<BSZ * (NXN / 4), 256, 0, stream>>>(pos, sq, idxw);

    kpack<<<(6 * 33 * 1024 + 255) / 256, 256, 0, stream>>>(mw1, mw1p, 264, 33, 6);
    kpack<<<(6 * 16 * 1024 + 255) / 256, 256, 0, stream>>>(mw2, mw2p, 128, 16, 6);
    kpack<<<(6 * 33 * 1024 + 255) / 256, 256, 0, stream>>>(uw1, uw1p, 261, 33, 6);
    kpack<<<(6 * 16 * 1024 + 255) / 256, 256, 0, stream>>>(uw2, uw2p, 128, 16, 6);

    kembed<<<NN, 128, 0, stream>>>(inputs, pos, params,
                                   emb_w1, emb_b1, emb_w2, emb_b2, f, fh);
    for (int l = 0; l < NLAY; l++) {
        hipMemsetAsync(p1, 0, 2 * BSZ * HD * sizeof(float), stream);
        kmsg8<<<NN / NPB, 256, 0, stream>>>(f, fh, fnew, inputs, pos, params, idxw,
                                            mw1p + l * 33 * 1024, mw1 + l * 264 * HD, mb1 + l * HD,
                                            mw2p + l * 16 * 1024, mb2 + l * HD,
                                            uw1p + l * 33 * 1024, uw1 + l * 261 * HD, ub1 + l * HD,
                                            uw2p + l * 16 * 1024, ub2 + l * HD,
                                            p1, p2);
        kapply<<<(BSZ * NXN * HD) / 256, 256, 0, stream>>>(fnew, p1, p2, f, fh);
    }
    khead<<<NN, 64, 0, stream>>>(f, inputs, ow1, ob1, ow2, ob2, out);
}

// Round 11
// 715.704 us; speedup vs baseline: 1.2940x; 1.2940x over previous
//
#include <hip/hip_runtime.h>
#include <math.h>

#define BSZ 4
#define NXN 4096
#define NPARP 5
#define HD 128
#define NLAY 6
#define KNN 16
#define DTC 0.1f
#define EPSC 1e-5f
#define NN (BSZ * NXN)
#define NPB 8          // nodes per block in kmsg4

typedef __attribute__((ext_vector_type(8))) short short8;
typedef __attribute__((ext_vector_type(4))) float f32x4;

#define XR(r) (((r) & 7) << 4)

// LDS byte offsets for kmsg4
#define OFF_E   0        // 128 x 256B  (fj bf16 -> h bf16)
#define OFF_AU  32768    // 16 x 512B   (update A: [fi | agg] bf16)
#define OFF_HU  40960    // 16 x 256B   (update hidden bf16)
#define OFF_DU  45056    // 128 f32
#define OFF_DPX 45568
#define OFF_DPY 46080
#define OFF_VAR 46592    // [8][8] f32
#define SMEMB   46848

__device__ __forceinline__ float swishf(float x) {
    return x / (1.0f + __expf(-x));
}

// round-to-nearest bf16 (weights only)
__device__ __forceinline__ unsigned short f2bf(float x) {
    union { float f; unsigned u; } v; v.f = x;
    unsigned r = v.u + 0x7fffu + ((v.u >> 16) & 1u);
    return (unsigned short)(r >> 16);
}
// truncation bf16 (activations; 1 VALU op)
__device__ __forceinline__ unsigned short trh(float x) {
    union { float f; unsigned u; } v; v.f = x;
    return (unsigned short)(v.u >> 16);
}

// ---------------- grid min/max per batch ----------------
__global__ void kminmax(const float* __restrict__ grid, float* __restrict__ gmm) {
    int b = blockIdx.x;
    int t = threadIdx.x;
    float mnx = 1e30f, mxx = -1e30f, mny = 1e30f, mxy = -1e30f;
    for (int n = t; n < NXN; n += 256) {
        float x = grid[(b * NXN + n) * 2 + 0];
        float y = grid[(b * NXN + n) * 2 + 1];
        mnx = fminf(mnx, x); mxx = fmaxf(mxx, x);
        mny = fminf(mny, y); mxy = fmaxf(mxy, y);
    }
    __shared__ float s[4][256];
    s[0][t] = mnx; s[1][t] = mxx; s[2][t] = mny; s[3][t] = mxy;
    __syncthreads();
    for (int off = 128; off > 0; off >>= 1) {
        if (t < off) {
            s[0][t] = fminf(s[0][t], s[0][t + off]);
            s[1][t] = fmaxf(s[1][t], s[1][t + off]);
            s[2][t] = fminf(s[2][t], s[2][t + off]);
            s[3][t] = fmaxf(s[3][t], s[3][t + off]);
        }
        __syncthreads();
    }
    if (t == 0) {
        gmm[b * 4 + 0] = s[0][0];
        gmm[b * 4 + 1] = s[1][0];
        gmm[b * 4 + 2] = s[2][0];
        gmm[b * 4 + 3] = s[3][0];
    }
}

// ---------------- pos + sq ----------------
__global__ void kpos(const float* __restrict__ grid, const float* __restrict__ gmm,
                     float* __restrict__ pos, float* __restrict__ sq) {
    int g = blockIdx.x * 256 + threadIdx.x;
    if (g >= NN) return;
    int b = g >> 12;
    float gx = grid[g * 2], gy = grid[g * 2 + 1];
    float px = (gx - gmm[b * 4 + 0]) / (gmm[b * 4 + 1] - gmm[b * 4 + 0]);
    float py = (gy - gmm[b * 4 + 2]) / (gmm[b * 4 + 3] - gmm[b * 4 + 2]);
    pos[g * 2] = px; pos[g * 2 + 1] = py;
    sq[g] = __fadd_rn(__fmul_rn(px, px), __fmul_rn(py, py));
}

// ---------------- KNN: one wave per node, chunked LDS, 16 extraction rounds ----
__global__ __launch_bounds__(256) void kknnC(const float* __restrict__ pos,
                                             const float* __restrict__ sq,
                                             int* __restrict__ idxw) {
    __shared__ float2 sxy[1024];
    __shared__ float ssq[1024];
    int blk = blockIdx.x;
    int b = blk >> 10;
    int t = threadIdx.x;
    int lane = t & 63, w = t >> 6;
    int i = (blk & 1023) * 4 + w;
    float2 pi = *(const float2*)&pos[(b * NXN + i) * 2];
    float sqi = sq[b * NXN + i];
    float pk[64];
    float g[4];
#pragma unroll
    for (int c = 0; c < 4; ++c) {
        __syncthreads();
        for (int n = t; n < 1024; n += 256) {
            int j = b * NXN + c * 1024 + n;
            sxy[n] = *(const float2*)&pos[j * 2];
            ssq[n] = sq[j];
        }
        __syncthreads();
        float gc = 1e38f;
#pragma unroll
        for (int tt = 0; tt < 16; ++tt) {
            int n = tt * 64 + lane;
            float2 pj = sxy[n];
            float dot = fmaf(pi.x, pj.x, pi.y * pj.y);
            float d2 = (sqi + ssq[n]) - 2.0f * dot;
            d2 = (c * 1024 + n == i) ? 1e38f : d2;
            pk[c * 16 + tt] = d2;
            gc = fminf(gc, d2);
        }
        g[c] = gc;
    }
    int obase = (b * NXN + i) * KNN;
#pragma unroll 1
    for (int r = 0; r < KNN; ++r) {
        float m = fminf(fminf(g[0], g[1]), fminf(g[2], g[3]));
        float gm = m;
#pragma unroll
        for (int off = 1; off < 64; off <<= 1)
            gm = fminf(gm, __shfl_xor(gm, off));
        if (m == gm) {
            int jt = 0;
            if (g[0] == gm) {
                float ng = 1e38f;
#pragma unroll
                for (int tt = 0; tt < 16; ++tt) {
                    bool hit = (pk[tt] == gm);
                    jt = hit ? tt : jt;
                    pk[tt] = hit ? 1e38f : pk[tt];
                    ng = fminf(ng, pk[tt]);
                }
                g[0] = ng;
            }
            if (g[1] == gm) {
                float ng = 1e38f;
#pragma unroll
                for (int tt = 16; tt < 32; ++tt) {
                    bool hit = (pk[tt] == gm);
                    jt = hit ? tt : jt;
                    pk[tt] = hit ? 1e38f : pk[tt];
                    ng = fminf(ng, pk[tt]);
                }
                g[1] = ng;
            }
            if (g[2] == gm) {
                float ng = 1e38f;
#pragma unroll
                for (int tt = 32; tt < 48; ++tt) {
                    bool hit = (pk[tt] == gm);
                    jt = hit ? tt : jt;
                    pk[tt] = hit ? 1e38f : pk[tt];
                    ng = fminf(ng, pk[tt]);
                }
                g[2] = ng;
            }
            if (g[3] == gm) {
                float ng = 1e38f;
#pragma unroll
                for (int tt = 48; tt < 64; ++tt) {
                    bool hit = (pk[tt] == gm);
                    jt = hit ? tt : jt;
                    pk[tt] = hit ? 1e38f : pk[tt];
                    ng = fminf(ng, pk[tt]);
                }
                g[3] = ng;
            }
            idxw[obase + r] = ((jt >> 4) << 10) + ((jt & 15) << 6) + lane;
        }
    }
}

// ---------------- weight pack: W[K x 128] f32 -> bf16 [ceil8(K)][128][8] ----------------
__global__ void kpack(const float* __restrict__ src, unsigned short* __restrict__ dst,
                      int K, int KB, int nmat) {
    int g = blockIdx.x * 256 + threadIdx.x;
    int per = KB * 1024;
    if (g >= nmat * per) return;
    int mat = g / per, rem = g % per;
    int kb = rem >> 10, r2 = rem & 1023;
    int n = r2 >> 3, j = r2 & 7;
    int k = kb * 8 + j;
    float v = (k < K) ? src[(mat * K + k) * HD + n] : 0.0f;
    dst[g] = f2bf(v);
}

// ---------------- embedding MLP ----------------
__global__ __launch_bounds__(128) void kembed(const float* __restrict__ inputs,
                                              const float* __restrict__ pos,
                                              const float* __restrict__ params,
                                              const float* __restrict__ w1,
                                              const float* __restrict__ b1,
                                              const float* __restrict__ w2,
                                              const float* __restrict__ b2,
                                              float* __restrict__ f,
                                              unsigned short* __restrict__ fh) {
    __shared__ __align__(16) float sh[HD];
    int t = threadIdx.x;
    int g = blockIdx.x;
    float rw1[8];
#pragma unroll
    for (int k = 0; k < 8; k++) rw1[k] = w1[k * HD + t];
    float u = inputs[g];
    float px = pos[g * 2], py = pos[g * 2 + 1];
    float a = b1[t] + u * rw1[0] + px * rw1[1] + py * rw1[2];
#pragma unroll
    for (int j = 0; j < NPARP; j++) a += params[g * NPARP + j] * rw1[3 + j];
    sh[t] = swishf(a);
    __syncthreads();
    float a2 = b2[t];
    for (int k = 0; k < HD; k += 4) {
        float4 s4 = *(const float4*)&sh[k];
        a2 = fmaf(s4.x, w2[(k + 0) * HD + t], a2);
        a2 = fmaf(s4.y, w2[(k + 1) * HD + t], a2);
        a2 = fmaf(s4.z, w2[(k + 2) * HD + t], a2);
        a2 = fmaf(s4.w, w2[(k + 3) * HD + t], a2);
    }
    float fv = swishf(a2);
    f[g * HD + t] = fv;
    fh[g * HD + t] = trh(fv);
}

// ---------------- fused MFMA layer: col-split waves, prefetched weights ----------------
__global__ __launch_bounds__(256, 3) void kmsg4(
    const float* __restrict__ f, const unsigned short* __restrict__ fh,
    float* __restrict__ fnew,
    const float* __restrict__ inputs, const float* __restrict__ pos,
    const float* __restrict__ params, const int* __restrict__ idxw,
    const unsigned short* __restrict__ W1p, const float* __restrict__ W1r,
    const float* __restrict__ B1,
    const unsigned short* __restrict__ W2p, const float* __restrict__ B2,
    const unsigned short* __restrict__ U1p, const float* __restrict__ U1r,
    const float* __restrict__ UB1,
    const unsigned short* __restrict__ U2p, const float* __restrict__ UB2) {
    __shared__ __align__(16) char sm[SMEMB];
    int tid = threadIdx.x;
    int lane = tid & 63, w = tid >> 6;
    int l15 = lane & 15, l4 = lane >> 4;
    int bn0 = blockIdx.x * NPB;
    int base = bn0 & ~(NXN - 1);
    int r0 = w * 32;
    int c0 = w * 32 + l15, c1 = c0 + 16;
    float* sVAR = (float*)(sm + OFF_VAR);

    // ---- early weight loads: com (kb 0..15) + mm1 (kb 16..31) + scalars
    short8 bC0[4], bC1[4], bM10[4], bM11[4];
#pragma unroll
    for (int k = 0; k < 4; ++k) {
        bC0[k]  = *(const short8*)&W1p[((k * 4 + l4) * HD + c0) * 8];
        bC1[k]  = *(const short8*)&W1p[((k * 4 + l4) * HD + c1) * 8];
        bM10[k] = *(const short8*)&W1p[((16 + k * 4 + l4) * HD + c0) * 8];
        bM11[k] = *(const short8*)&W1p[((16 + k * 4 + l4) * HD + c1) * 8];
    }
    float vB1_0 = B1[c0], vB1_1 = B1[c1];
    float wdu0 = W1r[256 * HD + c0], wdx0 = W1r[257 * HD + c0], wdy0 = W1r[258 * HD + c0];
    float wdu1 = W1r[256 * HD + c1], wdx1 = W1r[257 * HD + c1], wdy1 = W1r[258 * HD + c1];
    float wv0[5], wv1[5];
#pragma unroll
    for (int j = 0; j < 5; ++j) {
        wv0[j] = W1r[(259 + j) * HD + c0];
        wv1[j] = W1r[(259 + j) * HD + c1];
    }
    float vB2_0 = B2[c0], vB2_1 = B2[c1];

    // ---- staging
    if (lane < 32) {               // du/dpx/dpy for edges r0..r0+31
        int e = r0 + lane;
        int nd = e >> 4;
        int gj = idxw[(bn0 + nd) * KNN + (e & 15)];
        int gn = base + gj;
        ((float*)(sm + OFF_DU))[e]  = inputs[bn0 + nd] - inputs[gn];
        ((float*)(sm + OFF_DPX))[e] = pos[(bn0 + nd) * 2]     - pos[gn * 2];
        ((float*)(sm + OFF_DPY))[e] = pos[(bn0 + nd) * 2 + 1] - pos[gn * 2 + 1];
    } else if (lane < 42) {        // var for nodes 2w, 2w+1
        int q = lane - 32;
        int nd = 2 * w + q / 5, j = q % 5;
        sVAR[nd * 8 + j] = params[(bn0 + nd) * NPARP + j];
    }
    {   // fi rows 2w,2w+1 -> sAU
        int r = 2 * w + (lane >> 5);
        int c4 = (lane & 31) * 4;
        uint2 v = *(const uint2*)&fh[(bn0 + r) * HD + c4];
        *(uint2*)(sm + OFF_AU + r * 512 + ((c4 * 2) ^ XR(r))) = v;
    }
    {   // zero sAU rows 8..15 (wave w: rows 8+2w, 9+2w)
        int r = 8 + 2 * w + (lane >> 5);
        int cz = (lane & 31) * 16;
        uint4 z = {0, 0, 0, 0};
        *(uint4*)(sm + OFF_AU + r * 512 + cz) = z;
    }
    {   // zero sHU rows 8..15
        int r = 8 + 2 * w + (lane >> 5);
        int cz = (lane & 31) * 8;
        uint2 z = {0, 0};
        *(uint2*)(sm + OFF_HU + r * 256 + cz) = z;
    }
    {   // gather fj rows r0..r0+31 (jj staggered by (r>>3)&3 to break 8-way bank conflict)
        int r = r0 + (lane >> 1), hf = lane & 1;
        int gj = idxw[(bn0 + (r >> 4)) * KNN + (r & 15)];
        const uint4* src = (const uint4*)&fh[(base + gj) * HD + hf * 64];
        char* drow = sm + OFF_E + r * 256;
        int st = ((r >> 3) & 3) * 2;
#pragma unroll
        for (int jj = 0; jj < 8; ++jj) {
            int jx = (jj + st) & 7;
            uint4 p = src[jx];
            *(uint4*)(drow + ((hf * 128 + jx * 16) ^ XR(r))) = p;
        }
    }
    __syncthreads();               // B1: staging complete

    // ---- com GEMM (single M-tile of nodes, wave's 2 col-tiles)
    f32x4 cm0 = {0.f, 0.f, 0.f, 0.f}, cm1 = {0.f, 0.f, 0.f, 0.f};
    {
        short8 afi[4];
#pragma unroll
        for (int k = 0; k < 4; ++k)
            afi[k] = *(short8*)(sm + OFF_AU + l15 * 512 + ((k * 64 + l4 * 16) ^ XR(l15)));
#pragma unroll
        for (int k = 0; k < 4; ++k) {
            cm0 = __builtin_amdgcn_mfma_f32_16x16x32_bf16(afi[k], bC0[k], cm0, 0, 0, 0);
            cm1 = __builtin_amdgcn_mfma_f32_16x16x32_bf16(afi[k], bC1[k], cm1, 0, 0, 0);
        }
    }
    if (l4 < 2) {                  // fold bias + var terms (valid node rows only)
#pragma unroll
        for (int reg = 0; reg < 4; ++reg) {
            int nd = l4 * 4 + reg;
            float s0 = vB1_0, s1 = vB1_1;
#pragma unroll
            for (int j = 0; j < 5; ++j) {
                float vv = sVAR[nd * 8 + j];
                s0 = fmaf(vv, wv0[j], s0);
                s1 = fmaf(vv, wv1[j], s1);
            }
            cm0[reg] += s0; cm1[reg] += s1;
        }
    }

    // prefetch mm2 weights (complete during mm1)
    short8 bM20[4], bM21[4];
#pragma unroll
    for (int k = 0; k < 4; ++k) {
        bM20[k] = *(const short8*)&W2p[((k * 4 + l4) * HD + c0) * 8];
        bM21[k] = *(const short8*)&W2p[((k * 4 + l4) * HD + c1) * 8];
    }

    // ---- mm1: per-m-tile pipeline (read A[m+1] before barrier m, write h[m] after)
    short8 aC[4], aN[4];
#pragma unroll
    for (int k = 0; k < 4; ++k)
        aC[k] = *(short8*)(sm + OFF_E + l15 * 256 + ((k * 64 + l4 * 16) ^ XR(l15)));
#pragma unroll
    for (int m = 0; m < 8; ++m) {
        f32x4 h0 = {0.f, 0.f, 0.f, 0.f}, h1 = {0.f, 0.f, 0.f, 0.f};
#pragma unroll
        for (int k = 0; k < 4; ++k) {
            h0 = __builtin_amdgcn_mfma_f32_16x16x32_bf16(aC[k], bM10[k], h0, 0, 0, 0);
            h1 = __builtin_amdgcn_mfma_f32_16x16x32_bf16(aC[k], bM11[k], h1, 0, 0, 0);
        }
        if (m < 7) {
#pragma unroll
            for (int k = 0; k < 4; ++k)
                aN[k] = *(short8*)(sm + OFF_E + ((m + 1) * 16 + l15) * 256 +
                                   ((k * 64 + l4 * 16) ^ XR(l15)));
        }
        float com0 = __shfl(cm0[m & 3], ((m >> 2) << 4) | l15);
        float com1 = __shfl(cm1[m & 3], ((m >> 2) << 4) | l15);
        float4 duv = *(const float4*)(sm + OFF_DU  + (m * 16 + l4 * 4) * 4);
        float4 dxv = *(const float4*)(sm + OFF_DPX + (m * 16 + l4 * 4) * 4);
        float4 dyv = *(const float4*)(sm + OFF_DPY + (m * 16 + l4 * 4) * 4);
        __syncthreads();           // barrier m: all waves have read rows m (and m+1)
#pragma unroll
        for (int reg = 0; reg < 4; ++reg) {
            int rr = m * 16 + l4 * 4 + reg;
            float d_u = ((const float*)&duv)[reg];
            float d_x = ((const float*)&dxv)[reg];
            float d_y = ((const float*)&dyv)[reg];
            float hv0 = h0[reg] + com0 + d_u * wdu0 + d_x * wdx0 + d_y * wdy0;
            *(unsigned short*)(sm + OFF_E + rr * 256 + ((c0 * 2) ^ XR(rr))) =
                trh(swishf(hv0));
            float hv1 = h1[reg] + com1 + d_u * wdu1 + d_x * wdx1 + d_y * wdy1;
            *(unsigned short*)(sm + OFF_E + rr * 256 + ((c1 * 2) ^ XR(rr))) =
                trh(swishf(hv1));
        }
        if (m < 7) {
#pragma unroll
            for (int k = 0; k < 4; ++k) aC[k] = aN[k];
        }
    }
    __syncthreads();               // h complete

    // prefetch upd1 weights + scalars (complete during mm2)
    short8 bU10[8], bU11[8];
#pragma unroll
    for (int k = 0; k < 8; ++k) {
        bU10[k] = *(const short8*)&U1p[((k * 4 + l4) * HD + c0) * 8];
        bU11[k] = *(const short8*)&U1p[((k * 4 + l4) * HD + c1) * 8];
    }
    float vUB1_0 = UB1[c0], vUB1_1 = UB1[c1];
    float uv0[5], uv1[5];
#pragma unroll
    for (int j = 0; j < 5; ++j) {
        uv0[j] = U1r[(256 + j) * HD + c0];
        uv1[j] = U1r[(256 + j) * HD + c1];
    }

    // ---- mm2 + mean -> agg (wave's 2 col-tiles, all 8 m-tiles)
#pragma unroll
    for (int m = 0; m < 8; ++m) {
        short8 hf4[4];
#pragma unroll
        for (int k = 0; k < 4; ++k)
            hf4[k] = *(short8*)(sm + OFF_E + (m * 16 + l15) * 256 +
                                ((k * 64 + l4 * 16) ^ XR(l15)));
        f32x4 s0 = {0.f, 0.f, 0.f, 0.f}, s1 = {0.f, 0.f, 0.f, 0.f};
#pragma unroll
        for (int k = 0; k < 4; ++k) {
            s0 = __builtin_amdgcn_mfma_f32_16x16x32_bf16(hf4[k], bM20[k], s0, 0, 0, 0);
            s1 = __builtin_amdgcn_mfma_f32_16x16x32_bf16(hf4[k], bM21[k], s1, 0, 0, 0);
        }
        float sum0 = swishf(s0[0] + vB2_0) + swishf(s0[1] + vB2_0)
                   + swishf(s0[2] + vB2_0) + swishf(s0[3] + vB2_0);
        float sum1 = swishf(s1[0] + vB2_1) + swishf(s1[1] + vB2_1)
                   + swishf(s1[2] + vB2_1) + swishf(s1[3] + vB2_1);
        sum0 += __shfl_xor(sum0, 16); sum0 += __shfl_xor(sum0, 32);
        sum1 += __shfl_xor(sum1, 16); sum1 += __shfl_xor(sum1, 32);
        if (lane < 16) {
            int ca = w * 32 + lane;
            *(unsigned short*)(sm + OFF_AU + m * 512 + ((256 + ca * 2) ^ XR(m))) =
                trh(sum0 * 0.0625f);
            *(unsigned short*)(sm + OFF_AU + m * 512 + ((256 + (ca + 16) * 2) ^ XR(m))) =
                trh(sum1 * 0.0625f);
        }
    }
    __syncthreads();               // agg complete

    // prefetch upd2 weights (complete during upd1)
    short8 bU20[4], bU21[4];
#pragma unroll
    for (int k = 0; k < 4; ++k) {
        bU20[k] = *(const short8*)&U2p[((k * 4 + l4) * HD + c0) * 8];
        bU21[k] = *(const short8*)&U2p[((k * 4 + l4) * HD + c1) * 8];
    }
    float vUB2_0 = UB2[c0], vUB2_1 = UB2[c1];

    // ---- upd1: K=256 ([fi|agg]) -> swish -> sHU
    {
        short8 au[8];
#pragma unroll
        for (int k = 0; k < 8; ++k)
            au[k] = *(short8*)(sm + OFF_AU + l15 * 512 + ((k * 64 + l4 * 16) ^ XR(l15)));
        f32x4 u0 = {0.f, 0.f, 0.f, 0.f}, u1 = {0.f, 0.f, 0.f, 0.f};
#pragma unroll
        for (int k = 0; k < 8; ++k) {
            u0 = __builtin_amdgcn_mfma_f32_16x16x32_bf16(au[k], bU10[k], u0, 0, 0, 0);
            u1 = __builtin_amdgcn_mfma_f32_16x16x32_bf16(au[k], bU11[k], u1, 0, 0, 0);
        }
        if (l4 < 2) {
#pragma unroll
            for (int reg = 0; reg < 4; ++reg) {
                int nd = l4 * 4 + reg;
                float s0 = vUB1_0, s1 = vUB1_1;
#pragma unroll
                for (int j = 0; j < 5; ++j) {
                    float vv = sVAR[nd * 8 + j];
                    s0 = fmaf(vv, uv0[j], s0);
                    s1 = fmaf(vv, uv1[j], s1);
                }
                *(unsigned short*)(sm + OFF_HU + nd * 256 + ((c0 * 2) ^ XR(nd))) =
                    trh(swishf(u0[reg] + s0));
                *(unsigned short*)(sm + OFF_HU + nd * 256 + ((c1 * 2) ^ XR(nd))) =
                    trh(swishf(u1[reg] + s1));
            }
        }
    }
    __syncthreads();               // hu complete

    // ---- upd2: K=128 -> residual -> fnew
    {
        short8 ah[4];
#pragma unroll
        for (int k = 0; k < 4; ++k)
            ah[k] = *(short8*)(sm + OFF_HU + l15 * 256 + ((k * 64 + l4 * 16) ^ XR(l15)));
        f32x4 o0 = {0.f, 0.f, 0.f, 0.f}, o1 = {0.f, 0.f, 0.f, 0.f};
#pragma unroll
        for (int k = 0; k < 4; ++k) {
            o0 = __builtin_amdgcn_mfma_f32_16x16x32_bf16(ah[k], bU20[k], o0, 0, 0, 0);
            o1 = __builtin_amdgcn_mfma_f32_16x16x32_bf16(ah[k], bU21[k], o1, 0, 0, 0);
        }
        if (l4 < 2) {
#pragma unroll
            for (int reg = 0; reg < 4; ++reg) {
                int nd = l4 * 4 + reg;
                int gi0 = (bn0 + nd) * HD + c0;
                fnew[gi0] = f[gi0] + swishf(o0[reg] + vUB2_0);
                int gi1 = (bn0 + nd) * HD + c1;
                fnew[gi1] = f[gi1] + swishf(o1[reg] + vUB2_1);
            }
        }
    }
}

// ---------------- instance norm: stats, finalize, apply ----------------
__global__ __launch_bounds__(256) void kstats(const float* __restrict__ fnew,
                                              float* __restrict__ p1, float* __restrict__ p2) {
    int blk = blockIdx.x;           // BSZ*32
    int b = blk >> 5;
    int ch = blk & 31;
    int t = threadIdx.x;
    int c = t & 127;
    int half = t >> 7;
    int nbase = ch * 128;
    float s1 = 0.0f, s2 = 0.0f;
    for (int n = half; n < 128; n += 2) {
        float v = fnew[((b * NXN) + (nbase + n)) * HD + c];
        s1 += v; s2 += v * v;
    }
    __shared__ float r1[256], r2[256];
    r1[t] = s1; r2[t] = s2;
    __syncthreads();
    if (half == 0) {
        s1 += r1[t + 128]; s2 += r2[t + 128];
        p1[blk * HD + c] = s1;
        p2[blk * HD + c] = s2;
    }
}

__global__ void kfinal(const float* __restrict__ p1, const float* __restrict__ p2,
                       float* __restrict__ mean, float* __restrict__ inv) {
    int g = blockIdx.x * 256 + threadIdx.x;
    if (g >= BSZ * HD) return;
    int b = g >> 7;
    int c = g & 127;
    float s1 = 0.0f, s2 = 0.0f;
#pragma unroll
    for (int ch = 0; ch < 32; ch++) {
        s1 += p1[(b * 32 + ch) * HD + c];
        s2 += p2[(b * 32 + ch) * HD + c];
    }
    float m = s1 * (1.0f / NXN);
    float v = s2 * (1.0f / NXN) - m * m;
    mean[g] = m;
    inv[g] = rsqrtf(v + EPSC);
}

__global__ void kapply(const float* __restrict__ fnew,
                       const float* __restrict__ mean, const float* __restrict__ inv,
                       float* __restrict__ f, unsigned short* __restrict__ fh) {
    int g = blockIdx.x * 256 + threadIdx.x;
    int b = g >> 19;
    int c = g & 127;
    float fv = (fnew[g] - mean[b * HD + c]) * inv[b * HD + c];
    f[g] = fv;
    fh[g] = trh(fv);
}

// ---------------- output head ----------------
__global__ __launch_bounds__(64) void khead(const float* __restrict__ f,
                                            const float* __restrict__ inputs,
                                            const float* __restrict__ ow1,
                                            const float* __restrict__ ob1,
                                            const float* __restrict__ ow2,
                                            const float* __restrict__ ob2,
                                            float* __restrict__ out) {
    int bn = blockIdx.x;
    int c = threadIdx.x;
    float a = ob1[c];
    for (int k = 0; k < HD; k++) a += f[bn * HD + k] * ow1[k * 64 + c];
    float v = swishf(a) * ow2[c];
#pragma unroll
    for (int off = 32; off > 0; off >>= 1) v += __shfl_down(v, off);
    if (c == 0) out[bn] = inputs[bn] + DTC * (v + ob2[0]);
}

extern "C" void kernel_launch(void* const* d_in, const int* in_sizes, int n_in,
                              void* d_out, int out_size, void* d_ws, size_t ws_size,
                              hipStream_t stream) {
    const float* inputs = (const float*)d_in[0];
    const float* params = (const float*)d_in[1];
    const float* grid   = (const float*)d_in[3];
    const float* emb_w1 = (const float*)d_in[4];
    const float* emb_b1 = (const float*)d_in[5];
    const float* emb_w2 = (const float*)d_in[6];
    const float* emb_b2 = (const float*)d_in[7];
    const float* mw1 = (const float*)d_in[8];
    const float* mb1 = (const float*)d_in[9];
    const float* mw2 = (const float*)d_in[10];
    const float* mb2 = (const float*)d_in[11];
    const float* uw1 = (const float*)d_in[12];
    const float* ub1 = (const float*)d_in[13];
    const float* uw2 = (const float*)d_in[14];
    const float* ub2 = (const float*)d_in[15];
    const float* ow1 = (const float*)d_in[16];
    const float* ob1 = (const float*)d_in[17];
    const float* ow2 = (const float*)d_in[18];
    const float* ob2 = (const float*)d_in[19];
    float* out = (float*)d_out;

    float* ws  = (float*)d_ws;
    float* pos = ws;                      // BS*NX*2
    float* sq  = pos + BSZ * NXN * 2;     // BS*NX
    float* f   = sq + BSZ * NXN;          // BS*NX*H
    float* fnew = f + BSZ * NXN * HD;     // BS*NX*H
    float* p1   = fnew + BSZ * NXN * HD;  // BS*32*H
    float* p2   = p1 + BSZ * 32 * HD;     // BS*32*H
    float* meanw = p2 + BSZ * 32 * HD;    // BS*H
    float* invw  = meanw + BSZ * HD;      // BS*H
    float* gmm  = invw + BSZ * HD;        // 16
    int* idxw   = (int*)(gmm + 16);       // BS*NX*K ints
    unsigned short* mw1p = (unsigned short*)(idxw + NN * KNN);  // 6*33*1024
    unsigned short* mw2p = mw1p + 6 * 33 * 1024;                // 6*16*1024
    unsigned short* uw1p = mw2p + 6 * 16 * 1024;                // 6*33*1024
    unsigned short* uw2p = uw1p + 6 * 33 * 1024;                // 6*16*1024
    unsigned short* fh   = uw2p + 6 * 16 * 1024;                // BS*NX*H bf16

    kminmax<<<BSZ, 256, 0, stream>>>(grid, gmm);
    kpos<<<NN / 256, 256, 0, stream>>>(grid, gmm, pos, sq);
    kknnC<<<BSZ * (NXN / 4), 256, 0, stream>>>(pos, sq, idxw);

    kpack<<<(6 * 33 * 1024 + 255) / 256, 256, 0, stream>>>(mw1, mw1p, 264, 33, 6);
    kpack<<<(6 * 16 * 1024 + 255) / 256, 256, 0, stream>>>(mw2, mw2p, 128, 16, 6);
    kpack<<<(6 * 33 * 1024 + 255) / 256, 256, 0, stream>>>(uw1, uw1p, 261, 33, 6);
    kpack<<<(6 * 16 * 1024 + 255) / 256, 256, 0, stream>>>(uw2, uw2p, 128, 16, 6);

    kembed<<<NN, 128, 0, stream>>>(inputs, pos, params,
                                   emb_w1, emb_b1, emb_w2, emb_b2, f, fh);
    for (int l = 0; l < NLAY; l++) {
        kmsg4<<<NN / NPB, 256, 0, stream>>>(f, fh, fnew, inputs, pos, params, idxw,
                                            mw1p + l * 33 * 1024, mw1 + l * 264 * HD, mb1 + l * HD,
                                            mw2p + l * 16 * 1024, mb2 + l * HD,
                                            uw1p + l * 33 * 1024, uw1 + l * 261 * HD, ub1 + l * HD,
                                            uw2p + l * 16 * 1024, ub2 + l * HD);
        kstats<<<BSZ * 32, 256, 0, stream>>>(fnew, p1, p2);
        kfinal<<<2, 256, 0, stream>>>(p1, p2, meanw, invw);
        kapply<<<(BSZ * NXN * HD) / 256, 256, 0, stream>>>(fnew, meanw, invw, f, fh);
    }
    khead<<<NN, 64, 0, stream>>>(f, inputs, ow1, ob1, ow2, ob2, out);
}